// Round 8
// baseline (263.000 us; speedup 1.0000x reference)
//
#include <hip/hip_runtime.h>
#include <math.h>

#define S_LEN 2048
#define D_DIM 64
#define NBH   32          // B*H = 2*16
#define TINV  0.125f      // 1/temperature
#define C2    0.18033688011112042f   // TINV * log2(e)

typedef float  f32x4   __attribute__((ext_vector_type(4)));
typedef float  f32x16  __attribute__((ext_vector_type(16)));
typedef short  s16x4   __attribute__((ext_vector_type(4)));
typedef short  s16x8   __attribute__((ext_vector_type(8)));
typedef unsigned u32x4 __attribute__((ext_vector_type(4)));
typedef __bf16 bf16x8  __attribute__((ext_vector_type(8)));

__device__ __forceinline__ short bfc(float f) {
  return __builtin_bit_cast(short, (__bf16)f);   // RNE; pairs fuse to v_cvt_pk_bf16_f32
}
__device__ __forceinline__ unsigned pk2(float lo, float hi) {
  return (unsigned)(unsigned short)bfc(lo) | ((unsigned)(unsigned short)bfc(hi) << 16);
}

__device__ __forceinline__ f32x4 mfma16(s16x8 a, s16x8 b, f32x4 c) {
  return __builtin_amdgcn_mfma_f32_16x16x32_bf16(
      __builtin_bit_cast(bf16x8, a), __builtin_bit_cast(bf16x8, b), c, 0, 0, 0);
}
__device__ __forceinline__ f32x16 mfma32(s16x8 a, s16x8 b, f32x16 c) {
  return __builtin_amdgcn_mfma_f32_32x32x16_bf16(
      __builtin_bit_cast(bf16x8, a), __builtin_bit_cast(bf16x8, b), c, 0, 0, 0);
}

// swizzled LDS address: 128B rows, byte ^= (row&7)<<4  (G4 conflict fix)
__device__ __forceinline__ short* ldsp(short* base, int row, int byteoff) {
  return (short*)((char*)base + row * 128 + (byteoff ^ ((row & 7) << 4)));
}

// ---------------------------------------------------------------------------
// prep: bid<1024 -> kb16[bh][t][d] = bf16(K); else vT[bh][d][t] = bf16(V^T)
// ---------------------------------------------------------------------------
__global__ __launch_bounds__(256) void prep(
    const float* __restrict__ k, const float* __restrict__ v,
    short* __restrict__ kb16, short* __restrict__ vT)
{
  const int bid = blockIdx.x;
  const int t   = bid & 1023;
  const int bh  = t >> 5;
  const int kt  = t & 31;
  const int tid = threadIdx.x;

  if (bid < 1024) {
    const int st  = tid >> 2;
    const int sd0 = (tid & 3) * 16;
    const float* kp = k + ((size_t)bh * S_LEN + kt * 64 + st) * D_DIM + sd0;
    s16x8 o0, o1;
    #pragma unroll
    for (int j = 0; j < 8; ++j) { o0[j] = bfc(kp[j]); o1[j] = bfc(kp[8 + j]); }
    short* dst = kb16 + ((size_t)bh * S_LEN + kt * 64 + st) * D_DIM + sd0;
    *(s16x8*)dst       = o0;
    *(s16x8*)(dst + 8) = o1;
  } else {
    const int vt0 = (tid & 15) * 4;
    const int vd0 = (tid >> 4) * 4;
    const float* vb = v + ((size_t)bh * S_LEN + kt * 64) * D_DIM;
    f32x4 vr[4];
    #pragma unroll
    for (int i = 0; i < 4; ++i)
      vr[i] = *(const f32x4*)(vb + (size_t)(vt0 + i) * D_DIM + vd0);
    #pragma unroll
    for (int j = 0; j < 4; ++j) {
      s16x4 pk;
      pk[0] = bfc(vr[0][j]); pk[1] = bfc(vr[1][j]);
      pk[2] = bfc(vr[2][j]); pk[3] = bfc(vr[3][j]);
      *(s16x4*)(vT + (size_t)(bh * 64 + vd0 + j) * S_LEN + kt * 64 + vt0) = pk;
    }
  }
}

// ---------------------------------------------------------------------------
// attn_fwd: per (bh, 64-row q tile). Loop1: 32x32 MFMA flash pass.
//   Loop2: recompute S^T (16x16), exp2-fold, stage P tile in wave-private LDS,
//   read back row-major and store 256B-contiguous segments via L2 (plain
//   cached stores -- the rocclr fill proves plain stores hit 6.5 TB/s).
// ---------------------------------------------------------------------------
__global__ __launch_bounds__(256, 4) void attn_fwd(
    const float* __restrict__ q, const short* __restrict__ kb16,
    const short* __restrict__ vT, const int* __restrict__ mask,
    float* __restrict__ attn_out, short* __restrict__ OT)
{
  __shared__ short KV[2][64][64];     // [0]=K tile [t][d], [1]=V^T tile [d][t]
  __shared__ float rspart[4][32];     // per-wave rowsum partials

  short* KlB = &KV[0][0][0];
  short* VlB = &KV[1][0][0];

  const int bid   = blockIdx.x;
  const int xcd   = bid & 7;
  const int chunk = bid >> 3;
  const int bh    = xcd * 4 + (chunk >> 5);
  const int qt    = chunk & 31;
  const int b     = bh >> 4;

  const int tid  = threadIdx.x;
  const int wave = tid >> 6;
  const int lane = tid & 63;
  const int lr   = lane & 15;
  const int lg   = lane >> 4;
  const int L31  = lane & 31;
  const int hi   = lane >> 5;
  const int Q0   = qt * 64;

  const int qtile = wave & 1;         // which 32-q half
  const int tt    = wave >> 1;        // which 32-t half of each kt tile

  const short* kbb  = kb16 + (size_t)bh * S_LEN * D_DIM;
  const short* vtb  = vT   + (size_t)bh * 64 * S_LEN;
  const int*   mrow = mask + b * S_LEN;

  // --- Q fragments (32x32 B-frag): col q = L31, k = ks*16 + hi*8 + j ---
  s16x8 aqv[4];
  {
    const float* qp = q + ((size_t)bh * S_LEN + Q0 + qtile * 32 + L31) * D_DIM + hi * 8;
    #pragma unroll
    for (int ks = 0; ks < 4; ++ks) {
      f32x4 x0 = *(const f32x4*)(qp + ks * 16);
      f32x4 x1 = *(const f32x4*)(qp + ks * 16 + 4);
      s16x8 f;
      #pragma unroll
      for (int j = 0; j < 4; ++j) { f[j] = bfc(x0[j]); f[4 + j] = bfc(x1[j]); }
      aqv[ks] = f;
    }
  }

  f32x16 oacc[2];
  #pragma unroll
  for (int dt = 0; dt < 2; ++dt)
    #pragma unroll
    for (int r = 0; r < 16; ++r) oacc[dt][r] = 0.f;
  float rs = 0.f;

  // staging map: thread covers row st, bytes [c0, c0+32) of the 128B row
  const int st = tid >> 2;
  const int c0 = (tid & 3) * 32;

  s16x8 kr0, kr1, vr0, vr1;
  kr0 = *(const s16x8*)(kbb + (size_t)st * D_DIM + c0 / 2);
  kr1 = *(const s16x8*)(kbb + (size_t)st * D_DIM + c0 / 2 + 8);
  vr0 = *(const s16x8*)(vtb + (size_t)st * S_LEN + c0 / 2);
  vr1 = *(const s16x8*)(vtb + (size_t)st * S_LEN + c0 / 2 + 8);

  // ---------------- loop 1 ----------------
  for (int kt = 0; kt < 32; ++kt) {
    __syncthreads();   // prior iteration's LDS reads complete
    *(s16x8*)ldsp(KlB, st, c0)      = kr0;
    *(s16x8*)ldsp(KlB, st, c0 + 16) = kr1;
    *(s16x8*)ldsp(VlB, st, c0)      = vr0;
    *(s16x8*)ldsp(VlB, st, c0 + 16) = vr1;
    __syncthreads();   // stage visible

    // prefetch next tile AFTER the barrier (drain lands next iteration)
    if (kt + 1 < 32) {
      kr0 = *(const s16x8*)(kbb + (size_t)((kt + 1) * 64 + st) * D_DIM + c0 / 2);
      kr1 = *(const s16x8*)(kbb + (size_t)((kt + 1) * 64 + st) * D_DIM + c0 / 2 + 8);
      vr0 = *(const s16x8*)(vtb + (size_t)st * S_LEN + (kt + 1) * 64 + c0 / 2);
      vr1 = *(const s16x8*)(vtb + (size_t)st * S_LEN + (kt + 1) * 64 + c0 / 2 + 8);
    }
    const unsigned long long mbits = __ballot(mrow[kt * 64 + lane] != 0);

    // S^T quadrant = K Q^T : rows t = tt*32 + (C-row map), cols q
    f32x16 sacc;
    #pragma unroll
    for (int r = 0; r < 16; ++r) sacc[r] = 0.f;
    #pragma unroll
    for (int ks = 0; ks < 4; ++ks) {
      s16x8 ak = *(const s16x8*)ldsp(KlB, tt * 32 + L31, ks * 32 + hi * 16);
      sacc = mfma32(ak, aqv[ks], sacc);
    }

    // masked exp in place, rowsum accumulate
    const unsigned mloc = (unsigned)(mbits >> (tt * 32 + hi * 4));
    #pragma unroll
    for (int r = 0; r < 16; ++r) {
      float e = __expf(sacc[r] * TINV);
      e = ((mloc >> ((r & 3) + 8 * (r >> 2))) & 1u) ? e : 0.f;
      rs += e;
      sacc[r] = e;
    }

    // P^T -> B-frags via cvt_pk pairs + permlane32_swap (no LDS)
    unsigned a0 = pk2(sacc[0], sacc[1]),   b0 = pk2(sacc[4], sacc[5]);
    unsigned a1 = pk2(sacc[2], sacc[3]),   b1 = pk2(sacc[6], sacc[7]);
    unsigned a2 = pk2(sacc[8], sacc[9]),   b2 = pk2(sacc[12], sacc[13]);
    unsigned a3 = pk2(sacc[10], sacc[11]), b3 = pk2(sacc[14], sacc[15]);
    asm volatile("v_permlane32_swap_b32 %0, %1" : "+v"(a0), "+v"(b0));
    asm volatile("v_permlane32_swap_b32 %0, %1" : "+v"(a1), "+v"(b1));
    asm volatile("v_permlane32_swap_b32 %0, %1" : "+v"(a2), "+v"(b2));
    asm volatile("v_permlane32_swap_b32 %0, %1" : "+v"(a3), "+v"(b3));
    const s16x8 pb0 = __builtin_bit_cast(s16x8, (u32x4){a0, a1, b0, b1});
    const s16x8 pb1 = __builtin_bit_cast(s16x8, (u32x4){a2, a3, b2, b3});

    // O^T += V^T P^T  (rows d, cols q; k = t)
    #pragma unroll
    for (int dt = 0; dt < 2; ++dt) {
      s16x8 bv0 = *(const s16x8*)ldsp(VlB, dt * 32 + L31, tt * 64 + hi * 16);
      s16x8 bv1 = *(const s16x8*)ldsp(VlB, dt * 32 + L31, tt * 64 + 32 + hi * 16);
      oacc[dt] = mfma32(bv0, pb0, oacc[dt]);
      oacc[dt] = mfma32(bv1, pb1, oacc[dt]);
    }
  }

  // ---- epilogue: cross-wave reductions (t halves) via LDS, once ----
  rs += __shfl_xor(rs, 32, 64);            // per-q over this wave's 32 t

  __syncthreads();                          // all frag reads done; KV reusable
  if (lane < 32) rspart[wave][lane] = rs;
  float* oex = (float*)&KV[0][0][0];        // 16 KB = 4096 floats
  if (wave >= 2) {
    #pragma unroll
    for (int dt = 0; dt < 2; ++dt)
      #pragma unroll
      for (int r = 0; r < 16; ++r)
        oex[(wave - 2) * 2048 + dt * 1024 + r * 64 + lane] = oacc[dt][r];
  }
  __syncthreads();

  if (wave < 2) {
    const float rsum = rspart[wave][L31] + rspart[wave + 2][L31];
    const float rinvq = 1.0f / rsum;
    #pragma unroll
    for (int dt = 0; dt < 2; ++dt)
      #pragma unroll
      for (int r = 0; r < 16; ++r) {
        const int d = dt * 32 + (r & 3) + 8 * (r >> 2) + 4 * hi;
        float val = (oacc[dt][r] + oex[wave * 2048 + dt * 1024 + r * 64 + lane]) * rinvq;
        OT[(size_t)(bh * 64 + d) * S_LEN + Q0 + wave * 32 + L31] = bfc(val);
      }
  }

  // l2r for loop2's row q = wave*16 + lr : attn = exp2(s*C2 + l2r)
  const int qin = (wave & 1) * 16 + lr;
  const float l2r = -__log2f(rspart[wave >> 1][qin] + rspart[(wave >> 1) + 2][qin]);

  __syncthreads();   // epilogue LDS reads done before loop2 staging reuses KV

  // --- loop2 Q fragments (16x16): row q = wave*16 + lr, k = kk*32+lg*8+j ---
  s16x8 aq[2];
  {
    const float* qp = q + ((size_t)bh * S_LEN + Q0 + wave * 16 + lr) * D_DIM + lg * 8;
    #pragma unroll
    for (int kk = 0; kk < 2; ++kk) {
      f32x4 x0 = *(const f32x4*)(qp + kk * 32);
      f32x4 x1 = *(const f32x4*)(qp + kk * 32 + 4);
      s16x8 f;
      #pragma unroll
      for (int j = 0; j < 4; ++j) { f[j] = bfc(x0[j]); f[4 + j] = bfc(x1[j]); }
      aq[kk] = f;
    }
  }

  // ---------------- loop 2: attn stream with LDS-transposed stores ----------
  // wave-private 4 KB slice: 16 rows x 256 B, byte ^= (row&7)<<4 swizzle
  char* stb = (char*)&KV[0][0][0] + wave * 4096;
  float* abase = attn_out + (size_t)bh * S_LEN * S_LEN + (size_t)(Q0 + wave * 16) * S_LEN;
  const int rrow = lane >> 4;          // readback: 4 rows per instruction
  const int rcol = lane & 15;          // 16 lanes x 16B = 256B contiguous

  for (int kt = 0; kt < 32; ++kt) {
    const unsigned long long mbits = __ballot(mrow[kt * 64 + lane] != 0);

    #pragma unroll
    for (int n = 0; n < 4; ++n) {
      f32x4 sacc = (f32x4){0.f, 0.f, 0.f, 0.f};
      #pragma unroll
      for (int kk = 0; kk < 2; ++kk) {
        s16x8 bk = *(const s16x8*)(kbb + (size_t)(kt * 64 + n * 16 + lr) * D_DIM +
                                   kk * 32 + lg * 8);
        sacc = mfma16(bk, aq[kk], sacc);
      }
      const unsigned nib = (unsigned)(mbits >> (n * 16 + lg * 4)) & 0xFu;
      f32x4 pv;
      #pragma unroll
      for (int reg = 0; reg < 4; ++reg) {
        float e = __builtin_amdgcn_exp2f(fmaf(sacc[reg], C2, l2r));
        pv[reg] = (nib & (1u << reg)) ? e : 0.f;
      }
      // stage: row lr, col bytes (n*64 + lg*16), swizzled
      *(f32x4*)(stb + lr * 256 + ((n * 64 + lg * 16) ^ ((lr & 7) << 4))) = pv;
    }

    // readback row-major; plain cached stores (L2 write-combines to full lines)
    #pragma unroll
    for (int i = 0; i < 4; ++i) {
      const int row = i * 4 + rrow;
      f32x4 val = *(const f32x4*)(stb + row * 256 + ((rcol * 16) ^ ((row & 7) << 4)));
      *(f32x4*)(abase + (size_t)row * S_LEN + kt * 64 + rcol * 4) = val;
    }
  }
}

// ---------------------------------------------------------------------------
// vo_gemm: out[bh][d][c] = sum_s vT[d][s] * OT[c][s]
// ---------------------------------------------------------------------------
__global__ __launch_bounds__(256) void vo_gemm(
    const short* __restrict__ vT, const short* __restrict__ OT,
    float* __restrict__ out)
{
  const int bh   = blockIdx.x;
  const int tid  = threadIdx.x;
  const int wave = tid >> 6;
  const int lane = tid & 63;
  const int lr   = lane & 15;
  const int lg   = lane >> 4;

  const short* vb = vT + (size_t)(bh * 64) * S_LEN;
  const short* ob = OT + (size_t)(bh * 64) * S_LEN;

  f32x4 acc[4];
  #pragma unroll
  for (int n = 0; n < 4; ++n) acc[n] = (f32x4){0.f, 0.f, 0.f, 0.f};

  for (int s = 0; s < S_LEN; s += 32) {
    s16x8 a = *(const s16x8*)&vb[(size_t)(wave * 16 + lr) * S_LEN + s + lg * 8];
    #pragma unroll
    for (int n = 0; n < 4; ++n) {
      s16x8 bo = *(const s16x8*)&ob[(size_t)(n * 16 + lr) * S_LEN + s + lg * 8];
      acc[n] = mfma16(a, bo, acc[n]);
    }
  }

  #pragma unroll
  for (int n = 0; n < 4; ++n) {
    #pragma unroll
    for (int reg = 0; reg < 4; ++reg) {
      const int d = wave * 16 + lg * 4 + reg;
      const int c = n * 16 + lr;
      out[(size_t)(bh * 64 + d) * 64 + c] = acc[n][reg];
    }
  }
}

extern "C" void kernel_launch(void* const* d_in, const int* in_sizes, int n_in,
                              void* d_out, int out_size, void* d_ws, size_t ws_size,
                              hipStream_t stream) {
  (void)in_sizes; (void)n_in; (void)out_size; (void)ws_size;
  const float* q    = (const float*)d_in[0];
  const float* k    = (const float*)d_in[1];
  const float* v    = (const float*)d_in[2];
  const int*   mask = (const int*)d_in[3];

  float* out  = (float*)d_out;
  float* attn = out + (size_t)NBH * 64 * 64;

  const size_t HS = (size_t)NBH * 64 * S_LEN;
  short* OT   = (short*)d_ws;                     // 8 MiB
  short* vT   = OT + HS;                          // 8 MiB
  short* kb16 = vT + HS;                          // 8 MiB

  prep<<<dim3(2048), dim3(256), 0, stream>>>(k, v, kb16, vT);
  attn_fwd<<<dim3(1024), dim3(256), 0, stream>>>(q, kb16, vT, mask, attn, OT);
  vo_gemm<<<dim3(NBH), dim3(256), 0, stream>>>(vT, OT, out);
}

// Round 9
// 221.610 us; speedup vs baseline: 1.1868x; 1.1868x over previous
//
#include <hip/hip_runtime.h>
#include <math.h>

#define S_LEN 2048
#define D_DIM 64
#define NBH   32          // B*H = 2*16
#define TINV  0.125f      // 1/temperature
#define C2    0.18033688011112042f   // TINV * log2(e)

typedef float  f32x4   __attribute__((ext_vector_type(4)));
typedef float  f32x16  __attribute__((ext_vector_type(16)));
typedef short  s16x4   __attribute__((ext_vector_type(4)));
typedef short  s16x8   __attribute__((ext_vector_type(8)));
typedef unsigned u32x4 __attribute__((ext_vector_type(4)));
typedef __bf16 bf16x8  __attribute__((ext_vector_type(8)));

__device__ __forceinline__ short bfc(float f) {
  return __builtin_bit_cast(short, (__bf16)f);   // RNE; pairs fuse to v_cvt_pk_bf16_f32
}
// single-instruction pack: lo->bits[15:0], hi->bits[31:16]
__device__ __forceinline__ unsigned pk2(float lo, float hi) {
  unsigned r;
  asm("v_cvt_pk_bf16_f32 %0, %1, %2" : "=v"(r) : "v"(lo), "v"(hi));
  return r;
}

__device__ __forceinline__ f32x4 mfma16(s16x8 a, s16x8 b, f32x4 c) {
  return __builtin_amdgcn_mfma_f32_16x16x32_bf16(
      __builtin_bit_cast(bf16x8, a), __builtin_bit_cast(bf16x8, b), c, 0, 0, 0);
}
__device__ __forceinline__ f32x16 mfma32(s16x8 a, s16x8 b, f32x16 c) {
  return __builtin_amdgcn_mfma_f32_32x32x16_bf16(
      __builtin_bit_cast(bf16x8, a), __builtin_bit_cast(bf16x8, b), c, 0, 0, 0);
}

// swizzled LDS address: 128B rows, byte ^= (row&7)<<4  (G4 conflict fix)
__device__ __forceinline__ short* ldsp(short* base, int row, int byteoff) {
  return (short*)((char*)base + row * 128 + (byteoff ^ ((row & 7) << 4)));
}

// ---------------------------------------------------------------------------
// prep: bid<1024 -> kb16[bh][t][d] = bf16(K); else vT[bh][d][t] = bf16(V^T)
// ---------------------------------------------------------------------------
__global__ __launch_bounds__(256) void prep(
    const float* __restrict__ k, const float* __restrict__ v,
    short* __restrict__ kb16, short* __restrict__ vT)
{
  const int bid = blockIdx.x;
  const int t   = bid & 1023;
  const int bh  = t >> 5;
  const int kt  = t & 31;
  const int tid = threadIdx.x;

  if (bid < 1024) {
    const int st  = tid >> 2;
    const int sd0 = (tid & 3) * 16;
    const float* kp = k + ((size_t)bh * S_LEN + kt * 64 + st) * D_DIM + sd0;
    s16x8 o0, o1;
    #pragma unroll
    for (int j = 0; j < 8; ++j) { o0[j] = bfc(kp[j]); o1[j] = bfc(kp[8 + j]); }
    short* dst = kb16 + ((size_t)bh * S_LEN + kt * 64 + st) * D_DIM + sd0;
    *(s16x8*)dst       = o0;
    *(s16x8*)(dst + 8) = o1;
  } else {
    const int vt0 = (tid & 15) * 4;
    const int vd0 = (tid >> 4) * 4;
    const float* vb = v + ((size_t)bh * S_LEN + kt * 64) * D_DIM;
    f32x4 vr[4];
    #pragma unroll
    for (int i = 0; i < 4; ++i)
      vr[i] = *(const f32x4*)(vb + (size_t)(vt0 + i) * D_DIM + vd0);
    #pragma unroll
    for (int j = 0; j < 4; ++j) {
      s16x4 pk;
      pk[0] = bfc(vr[0][j]); pk[1] = bfc(vr[1][j]);
      pk[2] = bfc(vr[2][j]); pk[3] = bfc(vr[3][j]);
      *(s16x4*)(vT + (size_t)(bh * 64 + vd0 + j) * S_LEN + kt * 64 + vt0) = pk;
    }
  }
}

// ---------------------------------------------------------------------------
// attn_fwd: per (bh, 64-row q tile). Loop1: 32x32 MFMA flash pass.
//   Loop2: recompute S^T (16x16), exp2-fold, stage P tile in wave-private LDS,
//   read back row-major, NT-store 256B-contiguous segments.
//   launch_bounds (256,3): VGPR cap 168 -- no spills (peak live ~130 > 128).
// ---------------------------------------------------------------------------
__global__ __launch_bounds__(256, 3) void attn_fwd(
    const float* __restrict__ q, const short* __restrict__ kb16,
    const short* __restrict__ vT, const int* __restrict__ mask,
    float* __restrict__ attn_out, short* __restrict__ OT)
{
  __shared__ short KV[2][64][64];     // [0]=K tile [t][d], [1]=V^T tile [d][t]
  __shared__ float rspart[4][32];     // per-wave rowsum partials

  short* KlB = &KV[0][0][0];
  short* VlB = &KV[1][0][0];

  const int bid   = blockIdx.x;
  const int xcd   = bid & 7;
  const int chunk = bid >> 3;
  const int bh    = xcd * 4 + (chunk >> 5);
  const int qt    = chunk & 31;
  const int b     = bh >> 4;

  const int tid  = threadIdx.x;
  const int wave = tid >> 6;
  const int lane = tid & 63;
  const int lr   = lane & 15;
  const int lg   = lane >> 4;
  const int L31  = lane & 31;
  const int hi   = lane >> 5;
  const int Q0   = qt * 64;

  const int qtile = wave & 1;         // which 32-q half
  const int tt    = wave >> 1;        // which 32-t half of each kt tile

  const short* kbb  = kb16 + (size_t)bh * S_LEN * D_DIM;
  const short* vtb  = vT   + (size_t)bh * 64 * S_LEN;
  const int*   mrow = mask + b * S_LEN;

  // --- Q fragments (32x32 B-frag): col q = L31, k = ks*16 + hi*8 + j ---
  s16x8 aqv[4];
  {
    const float* qp = q + ((size_t)bh * S_LEN + Q0 + qtile * 32 + L31) * D_DIM + hi * 8;
    #pragma unroll
    for (int ks = 0; ks < 4; ++ks) {
      f32x4 x0 = *(const f32x4*)(qp + ks * 16);
      f32x4 x1 = *(const f32x4*)(qp + ks * 16 + 4);
      s16x8 f;
      #pragma unroll
      for (int j = 0; j < 4; ++j) { f[j] = bfc(x0[j]); f[4 + j] = bfc(x1[j]); }
      aqv[ks] = f;
    }
  }

  f32x16 oacc[2];
  #pragma unroll
  for (int dt = 0; dt < 2; ++dt)
    #pragma unroll
    for (int r = 0; r < 16; ++r) oacc[dt][r] = 0.f;
  float rs = 0.f;

  // staging map: thread covers row st, bytes [c0, c0+32) of the 128B row
  const int st = tid >> 2;
  const int c0 = (tid & 3) * 32;

  s16x8 kr0, kr1, vr0, vr1;
  kr0 = *(const s16x8*)(kbb + (size_t)st * D_DIM + c0 / 2);
  kr1 = *(const s16x8*)(kbb + (size_t)st * D_DIM + c0 / 2 + 8);
  vr0 = *(const s16x8*)(vtb + (size_t)st * S_LEN + c0 / 2);
  vr1 = *(const s16x8*)(vtb + (size_t)st * S_LEN + c0 / 2 + 8);

  // ---------------- loop 1 ----------------
  for (int kt = 0; kt < 32; ++kt) {
    __syncthreads();   // prior iteration's LDS reads complete
    *(s16x8*)ldsp(KlB, st, c0)      = kr0;
    *(s16x8*)ldsp(KlB, st, c0 + 16) = kr1;
    *(s16x8*)ldsp(VlB, st, c0)      = vr0;
    *(s16x8*)ldsp(VlB, st, c0 + 16) = vr1;
    __syncthreads();   // stage visible

    // prefetch next tile AFTER the barrier (drain lands next iteration)
    if (kt + 1 < 32) {
      kr0 = *(const s16x8*)(kbb + (size_t)((kt + 1) * 64 + st) * D_DIM + c0 / 2);
      kr1 = *(const s16x8*)(kbb + (size_t)((kt + 1) * 64 + st) * D_DIM + c0 / 2 + 8);
      vr0 = *(const s16x8*)(vtb + (size_t)st * S_LEN + (kt + 1) * 64 + c0 / 2);
      vr1 = *(const s16x8*)(vtb + (size_t)st * S_LEN + (kt + 1) * 64 + c0 / 2 + 8);
    }
    const unsigned long long mbits = __ballot(mrow[kt * 64 + lane] != 0);

    // S^T quadrant = K Q^T : rows t = tt*32 + (C-row map), cols q
    f32x16 sacc;
    #pragma unroll
    for (int r = 0; r < 16; ++r) sacc[r] = 0.f;
    #pragma unroll
    for (int ks = 0; ks < 4; ++ks) {
      s16x8 ak = *(const s16x8*)ldsp(KlB, tt * 32 + L31, ks * 32 + hi * 16);
      sacc = mfma32(ak, aqv[ks], sacc);
    }

    // masked exp2 in place, rowsum accumulate  (exp(s/8) == exp2(s*C2))
    const unsigned mloc = (unsigned)(mbits >> (tt * 32 + hi * 4));
    #pragma unroll
    for (int r = 0; r < 16; ++r) {
      float e = __builtin_amdgcn_exp2f(sacc[r] * C2);
      e = ((mloc >> ((r & 3) + 8 * (r >> 2))) & 1u) ? e : 0.f;
      rs += e;
      sacc[r] = e;
    }

    // P^T -> B-frags via cvt_pk pairs + permlane32_swap (no LDS)
    unsigned a0 = pk2(sacc[0], sacc[1]),   b0 = pk2(sacc[4], sacc[5]);
    unsigned a1 = pk2(sacc[2], sacc[3]),   b1 = pk2(sacc[6], sacc[7]);
    unsigned a2 = pk2(sacc[8], sacc[9]),   b2 = pk2(sacc[12], sacc[13]);
    unsigned a3 = pk2(sacc[10], sacc[11]), b3 = pk2(sacc[14], sacc[15]);
    asm volatile("v_permlane32_swap_b32 %0, %1" : "+v"(a0), "+v"(b0));
    asm volatile("v_permlane32_swap_b32 %0, %1" : "+v"(a1), "+v"(b1));
    asm volatile("v_permlane32_swap_b32 %0, %1" : "+v"(a2), "+v"(b2));
    asm volatile("v_permlane32_swap_b32 %0, %1" : "+v"(a3), "+v"(b3));
    const s16x8 pb0 = __builtin_bit_cast(s16x8, (u32x4){a0, a1, b0, b1});
    const s16x8 pb1 = __builtin_bit_cast(s16x8, (u32x4){a2, a3, b2, b3});

    // O^T += V^T P^T  (rows d, cols q; k = t)
    #pragma unroll
    for (int dt = 0; dt < 2; ++dt) {
      s16x8 bv0 = *(const s16x8*)ldsp(VlB, dt * 32 + L31, tt * 64 + hi * 16);
      s16x8 bv1 = *(const s16x8*)ldsp(VlB, dt * 32 + L31, tt * 64 + 32 + hi * 16);
      oacc[dt] = mfma32(bv0, pb0, oacc[dt]);
      oacc[dt] = mfma32(bv1, pb1, oacc[dt]);
    }
  }

  // ---- epilogue: cross-wave reductions (t halves) via LDS, once ----
  rs += __shfl_xor(rs, 32, 64);            // per-q over this wave's 32 t

  __syncthreads();                          // all frag reads done; KV reusable
  if (lane < 32) rspart[wave][lane] = rs;
  float* oex = (float*)&KV[0][0][0];        // 16 KB = 4096 floats
  if (wave >= 2) {
    #pragma unroll
    for (int dt = 0; dt < 2; ++dt)
      #pragma unroll
      for (int r = 0; r < 16; ++r)
        oex[(wave - 2) * 2048 + dt * 1024 + r * 64 + lane] = oacc[dt][r];
  }
  __syncthreads();

  if (wave < 2) {
    const float rsum = rspart[wave][L31] + rspart[wave + 2][L31];
    const float rinvq = 1.0f / rsum;
    #pragma unroll
    for (int dt = 0; dt < 2; ++dt)
      #pragma unroll
      for (int r = 0; r < 16; ++r) {
        const int d = dt * 32 + (r & 3) + 8 * (r >> 2) + 4 * hi;
        float val = (oacc[dt][r] + oex[wave * 2048 + dt * 1024 + r * 64 + lane]) * rinvq;
        OT[(size_t)(bh * 64 + d) * S_LEN + Q0 + wave * 32 + L31] = bfc(val);
      }
  }

  // l2r for loop2's row q = wave*16 + lr : attn = exp2(s*C2 + l2r)
  const int qin = (wave & 1) * 16 + lr;
  const float l2r = -__log2f(rspart[wave >> 1][qin] + rspart[(wave >> 1) + 2][qin]);

  __syncthreads();   // epilogue LDS reads done before loop2 staging reuses KV

  // --- loop2 Q fragments (16x16): row q = wave*16 + lr, k = kk*32+lg*8+j ---
  s16x8 aq[2];
  {
    const float* qp = q + ((size_t)bh * S_LEN + Q0 + wave * 16 + lr) * D_DIM + lg * 8;
    #pragma unroll
    for (int kk = 0; kk < 2; ++kk) {
      f32x4 x0 = *(const f32x4*)(qp + kk * 32);
      f32x4 x1 = *(const f32x4*)(qp + kk * 32 + 4);
      s16x8 f;
      #pragma unroll
      for (int j = 0; j < 4; ++j) { f[j] = bfc(x0[j]); f[4 + j] = bfc(x1[j]); }
      aq[kk] = f;
    }
  }

  // ---------------- loop 2: attn stream with LDS-transposed stores ----------
  // wave-private 4 KB slice: 16 rows x 256 B, byte ^= (row&7)<<4 swizzle
  char* stb = (char*)&KV[0][0][0] + wave * 4096;
  float* abase = attn_out + (size_t)bh * S_LEN * S_LEN + (size_t)(Q0 + wave * 16) * S_LEN;
  const int rrow = lane >> 4;          // readback: 4 rows per instruction
  const int rcol = lane & 15;          // 16 lanes x 16B = 256B contiguous

  for (int kt = 0; kt < 32; ++kt) {
    const unsigned long long mbits = __ballot(mrow[kt * 64 + lane] != 0);

    #pragma unroll
    for (int n = 0; n < 4; ++n) {
      f32x4 sacc = (f32x4){0.f, 0.f, 0.f, 0.f};
      #pragma unroll
      for (int kk = 0; kk < 2; ++kk) {
        s16x8 bk = *(const s16x8*)(kbb + (size_t)(kt * 64 + n * 16 + lr) * D_DIM +
                                   kk * 32 + lg * 8);
        sacc = mfma16(bk, aq[kk], sacc);
      }
      const unsigned nib = (unsigned)(mbits >> (n * 16 + lg * 4)) & 0xFu;
      f32x4 pv;
      #pragma unroll
      for (int reg = 0; reg < 4; ++reg) {
        float e = __builtin_amdgcn_exp2f(fmaf(sacc[reg], C2, l2r));
        pv[reg] = (nib & (1u << reg)) ? e : 0.f;
      }
      // stage: row lr, col bytes (n*64 + lg*16), swizzled
      *(f32x4*)(stb + lr * 256 + ((n * 64 + lg * 16) ^ ((lr & 7) << 4))) = pv;
    }

    // readback row-major and NT-store full 256B segments (2 lines/row)
    #pragma unroll
    for (int i = 0; i < 4; ++i) {
      const int row = i * 4 + rrow;
      f32x4 val = *(const f32x4*)(stb + row * 256 + ((rcol * 16) ^ ((row & 7) << 4)));
      __builtin_nontemporal_store(val,
          (f32x4*)(abase + (size_t)row * S_LEN + kt * 64 + rcol * 4));
    }
  }
}

// ---------------------------------------------------------------------------
// vo_gemm: out[bh][d][c] = sum_s vT[d][s] * OT[c][s]
// ---------------------------------------------------------------------------
__global__ __launch_bounds__(256) void vo_gemm(
    const short* __restrict__ vT, const short* __restrict__ OT,
    float* __restrict__ out)
{
  const int bh   = blockIdx.x;
  const int tid  = threadIdx.x;
  const int wave = tid >> 6;
  const int lane = tid & 63;
  const int lr   = lane & 15;
  const int lg   = lane >> 4;

  const short* vb = vT + (size_t)(bh * 64) * S_LEN;
  const short* ob = OT + (size_t)(bh * 64) * S_LEN;

  f32x4 acc[4];
  #pragma unroll
  for (int n = 0; n < 4; ++n) acc[n] = (f32x4){0.f, 0.f, 0.f, 0.f};

  for (int s = 0; s < S_LEN; s += 32) {
    s16x8 a = *(const s16x8*)&vb[(size_t)(wave * 16 + lr) * S_LEN + s + lg * 8];
    #pragma unroll
    for (int n = 0; n < 4; ++n) {
      s16x8 bo = *(const s16x8*)&ob[(size_t)(n * 16 + lr) * S_LEN + s + lg * 8];
      acc[n] = mfma16(a, bo, acc[n]);
    }
  }

  #pragma unroll
  for (int n = 0; n < 4; ++n) {
    #pragma unroll
    for (int reg = 0; reg < 4; ++reg) {
      const int d = wave * 16 + lg * 4 + reg;
      const int c = n * 16 + lr;
      out[(size_t)(bh * 64 + d) * 64 + c] = acc[n][reg];
    }
  }
}

extern "C" void kernel_launch(void* const* d_in, const int* in_sizes, int n_in,
                              void* d_out, int out_size, void* d_ws, size_t ws_size,
                              hipStream_t stream) {
  (void)in_sizes; (void)n_in; (void)out_size; (void)ws_size;
  const float* q    = (const float*)d_in[0];
  const float* k    = (const float*)d_in[1];
  const float* v    = (const float*)d_in[2];
  const int*   mask = (const int*)d_in[3];

  float* out  = (float*)d_out;
  float* attn = out + (size_t)NBH * 64 * 64;

  const size_t HS = (size_t)NBH * 64 * S_LEN;
  short* OT   = (short*)d_ws;                     // 8 MiB
  short* vT   = OT + HS;                          // 8 MiB
  short* kb16 = vT + HS;                          // 8 MiB

  prep<<<dim3(2048), dim3(256), 0, stream>>>(k, v, kb16, vT);
  attn_fwd<<<dim3(1024), dim3(256), 0, stream>>>(q, kb16, vT, mask, attn, OT);
  vo_gemm<<<dim3(NBH), dim3(256), 0, stream>>>(vT, OT, out);
}